// Round 22
// baseline (210.108 us; speedup 1.0000x reference)
//
#include <hip/hip_runtime.h>
#include <math.h>

#define BDIM 2
#define SLEN 2048
#define NH 16
#define NKV 4
#define HD 128

typedef __attribute__((ext_vector_type(8))) short short8v;
typedef __attribute__((ext_vector_type(4))) short short4v;
typedef __attribute__((ext_vector_type(8))) __bf16 bf16x8;
typedef __attribute__((ext_vector_type(4))) float f32x4;
typedef __attribute__((ext_vector_type(16))) float f32x16;
typedef __attribute__((ext_vector_type(4))) unsigned int u32x4;

__device__ inline unsigned short f2bf(float x) {
  unsigned int u = __builtin_bit_cast(unsigned int, x);
  unsigned int r = (u + 0x7fffu + ((u >> 16) & 1u)) >> 16;
  return (unsigned short)r;
}
__device__ inline float bf2f(unsigned short b) {
  unsigned int u = ((unsigned int)b) << 16;
  return __builtin_bit_cast(float, u);
}
__device__ inline unsigned int pk2(float a, float b) {
  unsigned short ua = __builtin_bit_cast(unsigned short, (__bf16)a);
  unsigned short ub = __builtin_bit_cast(unsigned short, (__bf16)b);
  return (unsigned int)ua | ((unsigned int)ub << 16);
}

// ---------------------------------------------------------------------------
// bf16 MFMA GEMM (proven R20): 128x128, BK=32, 3-buffer ring, vmcnt(4),
// one barrier/iter, conflict-free (row>>1)&3 swizzle, zero bank conflicts.
// ---------------------------------------------------------------------------
template <bool BF16_OUT, bool SPLIT>
__global__ __launch_bounds__(256) void gemm_ring(
    const unsigned short* __restrict__ A, const unsigned short* __restrict__ Bt,
    void* __restrict__ C0, void* __restrict__ C1,
    int M, int N, int K, int Nsplit, int S0, int S1) {
  __shared__ __align__(16) unsigned short lds[3 * 8192];  // 49152 B
  const int t    = threadIdx.x;
  const int lane = t & 63;
  const int w    = t >> 6;
  const int lg   = lane >> 4, l15 = lane & 15;
  const int wr   = w >> 1,    wc  = w & 1;
  const int bm = blockIdx.y * 128, bn = blockIdx.x * 128;

  const int r0  = t >> 2;
  const int c8  = (t & 3) ^ ((r0 >> 1) & 3);
  const int dst = t * 8;
  const int rk  = (l15 >> 1) & 3;

#define STAGE(kt, b)                                                           \
  { _Pragma("unroll") for (int i = 0; i < 2; ++i) {                            \
      __builtin_amdgcn_global_load_lds(                                        \
          (const __attribute__((address_space(1))) unsigned int*)              \
              &A[(size_t)(bm + i * 64 + r0) * K + (kt) * 32 + c8 * 8],         \
          (__attribute__((address_space(3))) unsigned int*)                    \
              &lds[(b) * 8192 + i * 2048 + dst],                               \
          16, 0, 0);                                                           \
      __builtin_amdgcn_global_load_lds(                                        \
          (const __attribute__((address_space(1))) unsigned int*)              \
              &Bt[(size_t)(bn + i * 64 + r0) * K + (kt) * 32 + c8 * 8],        \
          (__attribute__((address_space(3))) unsigned int*)                    \
              &lds[(b) * 8192 + 4096 + i * 2048 + dst],                        \
          16, 0, 0);                                                           \
  } }

  f32x4 acc[4][4];
#pragma unroll
  for (int m = 0; m < 4; ++m)
#pragma unroll
    for (int n = 0; n < 4; ++n) acc[m][n] = (f32x4){0.f, 0.f, 0.f, 0.f};

  const int NT = K >> 5;
  STAGE(0, 0)
  STAGE(1, 1)
  int bc = 0;

  for (int kt = 0; kt < NT; ++kt) {
    if (kt + 1 < NT) {
      asm volatile("s_waitcnt vmcnt(4)" ::: "memory");
    } else {
      asm volatile("s_waitcnt vmcnt(0)" ::: "memory");
    }
    __builtin_amdgcn_s_barrier();
    __builtin_amdgcn_sched_barrier(0);

    if (kt + 2 < NT) {
      const int nb = bc + 2 >= 3 ? bc - 1 : bc + 2;
      STAGE(kt + 2, nb)
    }

    const unsigned short* As = &lds[bc * 8192];
    const unsigned short* Bs = As + 4096;
    bf16x8 a[4], b[4];
#pragma unroll
    for (int m = 0; m < 4; ++m) {
      const int row = wr * 64 + m * 16 + l15;
      a[m] = __builtin_bit_cast(bf16x8, *reinterpret_cast<const short8v*>(
          &As[row * 32 + ((lg ^ rk) * 8)]));
    }
#pragma unroll
    for (int n = 0; n < 4; ++n) {
      const int row = wc * 64 + n * 16 + l15;
      b[n] = __builtin_bit_cast(bf16x8, *reinterpret_cast<const short8v*>(
          &Bs[row * 32 + ((lg ^ rk) * 8)]));
    }
#pragma unroll
    for (int m = 0; m < 4; ++m)
#pragma unroll
      for (int n = 0; n < 4; ++n)
        acc[m][n] = __builtin_amdgcn_mfma_f32_16x16x32_bf16(a[m], b[n], acc[m][n], 0, 0, 0);

    bc = (bc + 1 >= 3) ? 0 : bc + 1;
  }

  void* dst_p;
  int col0, stride;
  if (!SPLIT || bn < Nsplit) {
    dst_p = C0; col0 = bn; stride = S0;
  } else {
    dst_p = C1; col0 = bn - Nsplit; stride = S1;
  }
#pragma unroll
  for (int m = 0; m < 4; ++m) {
#pragma unroll
    for (int j = 0; j < 4; ++j) {
      const size_t row = (size_t)(bm + wr * 64 + m * 16 + lg * 4 + j);
#pragma unroll
      for (int n = 0; n < 4; ++n) {
        const int col = col0 + wc * 64 + n * 16 + l15;
        if (BF16_OUT)
          ((unsigned short*)dst_p)[row * stride + col] = f2bf(acc[m][n][j]);
        else
          ((float*)dst_p)[row * stride + col] = acc[m][n][j];
      }
    }
  }
#undef STAGE
}

// ---------------------------------------------------------------------------
// Fused prep: weight transposes (bx<160) + x cast (bx in [160,224))
// + cos/sin table build (bx in [224,232)): tab[spos][dp] = (cos,sin) of
// spos * 10000^(-dp/64), same expf/sincosf sequence as the rope kernel.
// ---------------------------------------------------------------------------
__global__ __launch_bounds__(256) void prep_all(
    const float* __restrict__ x, const float* __restrict__ Wq,
    const float* __restrict__ Wk, const float* __restrict__ Wv,
    const float* __restrict__ Wo, unsigned short* __restrict__ xb,
    unsigned short* __restrict__ Wqkvt, unsigned short* __restrict__ Wot,
    float2* __restrict__ tab) {
  const int bx = blockIdx.x;
  if (bx >= 224) {  // rope table: 8*64 blocks * 256 thr = 131072 = 2048*64
    const int idx = ((bx - 224) * 64 + blockIdx.y) * 256 + threadIdx.x;
    const int spos = idx >> 6;
    const int dp   = idx & 63;
    const float inv_freq = expf(-(float)dp * (9.210340371976184f / 64.0f));
    float sn, cs;
    sincosf((float)spos * inv_freq, &sn, &cs);
    tab[idx] = make_float2(cs, sn);
    return;
  }
  if (bx >= 160) {  // x cast
    const int cb = (bx - 160) * 64 + blockIdx.y;
    const int i = (cb * 256 + threadIdx.x) * 8;
    float4 a = *reinterpret_cast<const float4*>(&x[i]);
    float4 b = *reinterpret_cast<const float4*>(&x[i + 4]);
    short8v s;
    s[0] = f2bf(a.x); s[1] = f2bf(a.y); s[2] = f2bf(a.z); s[3] = f2bf(a.w);
    s[4] = f2bf(b.x); s[5] = f2bf(b.y); s[6] = f2bf(b.z); s[7] = f2bf(b.w);
    *reinterpret_cast<short8v*>(&xb[i]) = s;
    return;
  }
  const float* W;
  unsigned short* Wt;
  int N, nb;
  if (bx < 64)      { W = Wq; Wt = Wqkvt;                          N = 2048; nb = bx; }
  else if (bx < 80) { W = Wk; Wt = Wqkvt + (size_t)2048 * 2048;    N = 512;  nb = bx - 64; }
  else if (bx < 96) { W = Wv; Wt = Wqkvt + (size_t)2560 * 2048;    N = 512;  nb = bx - 80; }
  else              { W = Wo; Wt = Wot;                            N = 2048; nb = bx - 96; }
  const int K = 2048;
  __shared__ float tile[32][33];
  const int tx = threadIdx.x & 31, ty = threadIdx.x >> 5;
  const int n0 = nb * 32, k0 = blockIdx.y * 32;
#pragma unroll
  for (int i = 0; i < 4; ++i)
    tile[ty + i * 8][tx] = W[(size_t)(k0 + ty + i * 8) * N + n0 + tx];
  __syncthreads();
#pragma unroll
  for (int i = 0; i < 4; ++i)
    Wt[(size_t)(n0 + ty + i * 8) * K + k0 + tx] = f2bf(tile[tx][ty + i * 8]);
}

// ---------------------------------------------------------------------------
// Fused mid: K RoPE+xPos (bid<4096, kvb offsets <512) + V pre-transpose
// (bid>=4096, kvb offsets >=512). Q rope moved into flash (table-based).
// ---------------------------------------------------------------------------
__global__ __launch_bounds__(256) void rope_tv_all(
    unsigned short* __restrict__ kvb, unsigned short* __restrict__ vt) {
  const int bid = blockIdx.x;
  __shared__ unsigned short tile[64][136];
  if (bid >= 4096) {  // transpose_v region
    const int lb  = bid - 4096;
    const int st  = lb & 31;
    const int kvh = (lb >> 5) & 3;
    const int b   = lb >> 7;
    const int t = threadIdx.x;
#pragma unroll
    for (int i = 0; i < 4; ++i) {
      const int idx = t + i * 256;
      const int s   = idx >> 4;
      const int d0  = (idx & 15) * 8;
      short8v v = *reinterpret_cast<const short8v*>(
          &kvb[((size_t)(b * SLEN + st * 64 + s)) * 1024 + 512 + kvh * 128 + d0]);
      *reinterpret_cast<short8v*>(&tile[s][d0]) = v;
    }
    __syncthreads();
#pragma unroll
    for (int i = 0; i < 4; ++i) {
      const int idx = t + i * 256;
      const int d   = idx >> 3;
      const int cc  = idx & 7;
      const int cs  = cc ^ (d & 7);
      short8v o;
#pragma unroll
      for (int j = 0; j < 8; ++j) o[j] = (short)tile[cs * 8 + j][d];
      *reinterpret_cast<short8v*>(
          &vt[(((size_t)(b * 4 + kvh) * 128 + d) * 2048) + st * 64 + cc * 8]) = o;
    }
    return;
  }
  // K rope region (inverted xpos, no extra scale)
  const int idx = bid * 256 + threadIdx.x;
  const int dp  = idx & 63;
  const int tmp = idx >> 6;
  const int h   = tmp & 3;
  const int row = tmp >> 2;
  const int s   = row & (SLEN - 1);

  const float inv_freq = expf(-(float)dp * (9.210340371976184f / 64.0f));
  const float ang = (float)s * inv_freq;
  float sn, cs;
  sincosf(ang, &sn, &cs);

  unsigned short* p = kvb + (size_t)row * 1024 + h * HD;
  const float x0 = bf2f(p[dp]);
  const float x1 = bf2f(p[dp + 64]);
  float y0 = x0 * cs - x1 * sn;
  float y1 = x1 * cs + x0 * sn;

  const float scl = ((float)s + 256.0f) / 512.0f;
  const float se_even = 1.0f / scl;
  const float se_odd  = scl;
  const float se = (dp & 1) ? se_odd : se_even;

  p[dp]      = f2bf(y0 * se);
  p[dp + 64] = f2bf(y1 * se);
}

// ---------------------------------------------------------------------------
// Flash attention v13: v12 + table-based Q RoPE/xPos fused into the Q load
// (math identical to the v11-proven fusion; sincosf replaced by table).
// ---------------------------------------------------------------------------
__global__ __launch_bounds__(512) void flash_attn_v13(
    const unsigned short* __restrict__ qb, const unsigned short* __restrict__ kvb,
    const unsigned short* __restrict__ vt, const float2* __restrict__ tab,
    unsigned short* __restrict__ o) {
  const int bid = blockIdx.x;
  const int u   = bid & 7;
  const int bh  = bid >> 3;
  const int h   = bh & (NH - 1);
  const int b   = bh >> 4;
  const int kvh = h >> 2;

  __shared__ __align__(16) unsigned char smem[131072];

  const int t    = threadIdx.x;
  const int lane = t & 63;
  const int w    = t >> 6;
  const int par  = w >> 2;
  const int wq   = w & 3;
  const int hi   = lane >> 5;
  const int l31  = lane & 31;

  const size_t bS = (size_t)b * SLEN;
  const size_t vbase = (size_t)(b * 4 + kvh) * 128;

  int krow[2], kgrp[2];
#pragma unroll
  for (int i = 0; i < 2; ++i) {
    const int slot = w * 2048 + i * 1024 + lane * 16;
    krow[i] = slot >> 8;
    kgrp[i] = (slot >> 4) & 15;
  }
  int vrow[2], vchk[2];
#pragma unroll
  for (int i = 0; i < 2; ++i) {
    const int slot = w * 2048 + i * 1024 + lane * 16;
    vrow[i] = slot >> 7;
    vchk[i] = (slot >> 4) & 7;
  }

#define K_STAGE(kt, bufk)                                                      \
  { _Pragma("unroll") for (int i = 0; i < 2; ++i) {                            \
      const unsigned short* ksrc = &kvb[(bS + (size_t)(kt) * 64 + krow[i]) * 1024 \
          + kvh * 128 + ((kgrp[i] ^ (krow[i] & 15)) << 3)];                    \
      __builtin_amdgcn_global_load_lds(                                        \
          (const __attribute__((address_space(1))) unsigned int*)ksrc,         \
          (__attribute__((address_space(3))) unsigned int*)                    \
              (smem + (bufk) * 16384 + w * 2048 + i * 1024),                   \
          16, 0, 0); } }

#define V_STAGE(kt, bufk)                                                      \
  { _Pragma("unroll") for (int i = 0; i < 2; ++i) {                            \
      const unsigned short* vsrc = &vt[(vbase + vrow[i]) * 2048                \
          + (size_t)(kt) * 64 + vchk[i] * 8];                                  \
      __builtin_amdgcn_global_load_lds(                                        \
          (const __attribute__((address_space(1))) unsigned int*)vsrc,         \
          (__attribute__((address_space(3))) unsigned int*)                    \
              (smem + 65536 + (bufk) * 16384 + w * 2048 + i * 1024),           \
          16, 0, 0); } }

  for (int half = 0; half < 2; ++half) {
    const int qt2 = half ? (15 - u) : u;

    // ---- Q fragments + table-based RoPE/xPos (pair = frags c, c+4)
    bf16x8 qf[8];
    {
      const int spos = qt2 * 128 + wq * 32 + l31;
      const size_t qrow = (bS + spos) * 2048 + (size_t)h * HD;
      short8v qr[8];
#pragma unroll
      for (int c = 0; c < 8; ++c)
        qr[c] = *reinterpret_cast<const short8v*>(&qb[qrow + c * 16 + hi * 8]);
      const float scl = ((float)spos + 256.0f) / 512.0f;
      const float se_e = scl * 0.088388347648318447f;
      const float se_o = (1.0f / scl) * 0.088388347648318447f;
      const float2* trow = &tab[spos * 64];
#pragma unroll
      for (int c = 0; c < 4; ++c) {
        short8v nlo, nhi;
#pragma unroll
        for (int j = 0; j < 8; ++j) {
          const int dp = c * 16 + hi * 8 + j;
          const float2 cssn = trow[dp];
          const float x0 = bf2f((unsigned short)qr[c][j]);
          const float x1 = bf2f((unsigned short)qr[c + 4][j]);
          const float se = (j & 1) ? se_o : se_e;
          nlo[j] = (short)f2bf((x0 * cssn.x - x1 * cssn.y) * se);
          nhi[j] = (short)f2bf((x1 * cssn.x + x0 * cssn.y) * se);
        }
        qf[c]     = __builtin_bit_cast(bf16x8, nlo);
        qf[c + 4] = __builtin_bit_cast(bf16x8, nhi);
      }
    }

    f32x16 Od[4];
#pragma unroll
    for (int ds = 0; ds < 4; ++ds)
#pragma unroll
      for (int r = 0; r < 16; ++r) Od[ds][r] = 0.f;
    float m_run = -1e30f, l_run = 0.f;

    K_STAGE(0, 0)
    K_STAGE(1, 1)
    V_STAGE(0, 0)
    V_STAGE(1, 1)
    __syncthreads();

    for (int e = 0; e <= qt2; ++e) {
      const int s = e & 1;
      const int kt = 2 * e + par;
      const bool more = (e < qt2);
      if (more) {
        K_STAGE(2 * e + 2, (s ^ 1) * 2 + 0)
        K_STAGE(2 * e + 3, (s ^ 1) * 2 + 1)
        V_STAGE(2 * e + 2, (s ^ 1) * 2 + 0)
        V_STAGE(2 * e + 3, (s ^ 1) * 2 + 1)
      }
      const unsigned short* Kb = (const unsigned short*)(smem + (s * 2 + par) * 16384);
      const unsigned int*   Vw = (const unsigned int*)(smem + 65536 + (s * 2 + par) * 16384);

      f32x16 Sa, Sb;
#pragma unroll
      for (int r = 0; r < 16; ++r) { Sa[r] = 0.f; Sb[r] = 0.f; }
      __builtin_amdgcn_s_setprio(1);
#pragma unroll
      for (int c = 0; c < 8; ++c) {
        const int ra = l31, rb = 32 + l31;
        bf16x8 ka = __builtin_bit_cast(bf16x8, *reinterpret_cast<const short8v*>(
            &Kb[ra * 128 + (((2 * c + hi) ^ (ra & 15)) << 3)]));
        bf16x8 kb2 = __builtin_bit_cast(bf16x8, *reinterpret_cast<const short8v*>(
            &Kb[rb * 128 + (((2 * c + hi) ^ (rb & 15)) << 3)]));
        Sa = __builtin_amdgcn_mfma_f32_32x32x16_bf16(ka, qf[c], Sa, 0, 0, 0);
        Sb = __builtin_amdgcn_mfma_f32_32x32x16_bf16(kb2, qf[c], Sb, 0, 0, 0);
      }
      __builtin_amdgcn_s_setprio(0);

      if (kt >= 2 * qt2) {
        const int thresh = qt2 * 128 + wq * 32 + l31 - kt * 64;
#pragma unroll
        for (int r = 0; r < 16; ++r) {
          const int kla = (r & 3) + 8 * (r >> 2) + 4 * hi;
          if (kla > thresh) Sa[r] = -INFINITY;
          if (kla + 32 > thresh) Sb[r] = -INFINITY;
        }
      }

      float pmax = Sa[0];
#pragma unroll
      for (int r = 0; r < 16; ++r) pmax = fmaxf(pmax, fmaxf(Sa[r], Sb[r]));
      pmax = fmaxf(pmax, __shfl_xor(pmax, 32));

      const bool defer = __all(pmax - m_run <= 8.0f);
      float m_new, f;
      if (defer) {
        m_new = m_run; f = 1.0f;
      } else {
        m_new = fmaxf(m_run, pmax);
        f = __expf(m_run - m_new);
        m_run = m_new;
      }

      float psum = 0.f;
#pragma unroll
      for (int r = 0; r < 16; ++r) {
        Sa[r] = __expf(Sa[r] - m_new);
        Sb[r] = __expf(Sb[r] - m_new);
        psum += Sa[r] + Sb[r];
      }
      psum += __shfl_xor(psum, 32);
      l_run = l_run * f + psum;

      if (!defer) {
#pragma unroll
        for (int ds = 0; ds < 4; ++ds)
#pragma unroll
          for (int r = 0; r < 16; ++r) Od[ds][r] *= f;
      }

#pragma unroll
      for (int kc = 0; kc < 4; ++kc) {
        const int Zz = kc & 1;
        f32x16 Sx = (kc >> 1) ? Sb : Sa;
        unsigned int W00 = pk2(Sx[4 * (2 * Zz + 0) + 0], Sx[4 * (2 * Zz + 0) + 1]);
        unsigned int W01 = pk2(Sx[4 * (2 * Zz + 0) + 2], Sx[4 * (2 * Zz + 0) + 3]);
        unsigned int W10 = pk2(Sx[4 * (2 * Zz + 1) + 0], Sx[4 * (2 * Zz + 1) + 1]);
        unsigned int W11 = pk2(Sx[4 * (2 * Zz + 1) + 2], Sx[4 * (2 * Zz + 1) + 3]);
        unsigned int X00 = __shfl_xor(W00, 32), X01 = __shfl_xor(W01, 32);
        unsigned int X10 = __shfl_xor(W10, 32), X11 = __shfl_xor(W11, 32);
        u32x4 pv;
        pv[0] = hi ? X10 : W00;
        pv[1] = hi ? X11 : W01;
        pv[2] = hi ? W10 : X00;
        pv[3] = hi ? W11 : X01;
        bf16x8 pf = __builtin_bit_cast(bf16x8, pv);
        __builtin_amdgcn_s_setprio(1);
#pragma unroll
        for (int ds = 0; ds < 4; ++ds) {
          const int d = ds * 32 + l31;
          u32x4 vv = *reinterpret_cast<const u32x4*>(
              &Vw[d * 32 + ((kc * 8 + hi * 4) ^ ((d & 7) << 2))]);
          bf16x8 vf = __builtin_bit_cast(bf16x8, vv);
          Od[ds] = __builtin_amdgcn_mfma_f32_32x32x16_bf16(vf, pf, Od[ds], 0, 0, 0);
        }
        __builtin_amdgcn_s_setprio(0);
      }

      __syncthreads();
    }

    float* mf = (float*)smem;
    float* Of = (float*)(smem + 2048);
    if (par == 1) {
      mf[(wq * 2 + 0) * 64 + lane] = m_run;
      mf[(wq * 2 + 1) * 64 + lane] = l_run;
    }
    float fe = 0.f, fo = 0.f, linv = 0.f;
#pragma unroll
    for (int p = 0; p < 2; ++p) {
      if (par == 1) {
#pragma unroll
        for (int d2 = 0; d2 < 2; ++d2)
#pragma unroll
          for (int r = 0; r < 16; ++r)
            Of[((wq * 2 + d2) * 16 + r) * 64 + lane] = Od[p * 2 + d2][r];
      }
      __syncthreads();
      if (par == 0) {
        if (p == 0) {
          const float m_o = mf[(wq * 2 + 0) * 64 + lane];
          const float l_o = mf[(wq * 2 + 1) * 64 + lane];
          const float mm = fmaxf(m_run, m_o);
          fe = __expf(m_run - mm);
          fo = __expf(m_o - mm);
          linv = 1.0f / (l_run * fe + l_o * fo);
        }
        const size_t row = bS + qt2 * 128 + wq * 32 + l31;
#pragma unroll
        for (int d2 = 0; d2 < 2; ++d2) {
          const int ds = p * 2 + d2;
#pragma unroll
          for (int g = 0; g < 4; ++g) {
            short4v ov;
#pragma unroll
            for (int j = 0; j < 4; ++j) {
              const int r = g * 4 + j;
              const float val = (Od[ds][r] * fe +
                                 Of[((wq * 2 + d2) * 16 + r) * 64 + lane] * fo) * linv;
              ov[j] = (short)__builtin_bit_cast(unsigned short, (__bf16)val);
            }
            const int dbase = ds * 32 + 8 * g + 4 * hi;
            *reinterpret_cast<short4v*>(&o[row * 2048 + h * HD + dbase]) = ov;
          }
        }
      }
      __syncthreads();
    }
  }  // half loop
#undef K_STAGE
#undef V_STAGE
}

// ---------------------------------------------------------------------------
extern "C" void kernel_launch(void* const* d_in, const int* in_sizes, int n_in,
                              void* d_out, int out_size, void* d_ws, size_t ws_size,
                              hipStream_t stream) {
  (void)in_sizes; (void)n_in; (void)out_size; (void)ws_size;
  const float* x  = (const float*)d_in[0];
  const float* Wq = (const float*)d_in[1];
  const float* Wk = (const float*)d_in[2];
  const float* Wv = (const float*)d_in[3];
  const float* Wo = (const float*)d_in[4];
  float* out = (float*)d_out;

  unsigned char* ws = (unsigned char*)d_ws;
  const size_t MB = 1024 * 1024;
  unsigned short* xb    = (unsigned short*)(ws);            // 16 MB 4096x2048
  unsigned short* Wqkvt = (unsigned short*)(ws + 16 * MB);  // 12 MB 3072x2048
  unsigned short* Wot   = (unsigned short*)(ws + 28 * MB);  //  8 MB 2048x2048
  unsigned short* qb    = (unsigned short*)(ws + 36 * MB);  // 16 MB 4096x2048
  unsigned short* kvb   = (unsigned short*)(ws + 52 * MB);  //  8 MB 4096x1024
  unsigned short* attn  = (unsigned short*)(ws + 60 * MB);  // 16 MB
  unsigned short* vtb   = (unsigned short*)(ws + 76 * MB);  //  4 MB 1024x2048
  float2*         tab   = (float2*)(ws + 80 * MB);          //  1 MB 2048x64

  const int M = BDIM * SLEN;  // 4096
  dim3 blk(256);

  prep_all<<<dim3(232, 64), blk, 0, stream>>>(
      x, Wq, Wk, Wv, Wo, xb, Wqkvt, Wot, tab);

  gemm_ring<true, true><<<dim3(24, 32), blk, 0, stream>>>(
      xb, Wqkvt, qb, kvb, M, 3072, 2048, 2048, 2048, 1024);

  rope_tv_all<<<4352, blk, 0, stream>>>(kvb, vtb);

  flash_attn_v13<<<BDIM * NH * 8, dim3(512), 0, stream>>>(qb, kvb, vtb, tab, attn);

  gemm_ring<false, false><<<dim3(16, 32), blk, 0, stream>>>(
      attn, Wot, out, nullptr, M, 2048, 2048, 2048, 2048, 0);
}

// Round 23
// 207.733 us; speedup vs baseline: 1.0114x; 1.0114x over previous
//
#include <hip/hip_runtime.h>
#include <math.h>

#define BDIM 2
#define SLEN 2048
#define NH 16
#define NKV 4
#define HD 128

typedef __attribute__((ext_vector_type(8))) short short8v;
typedef __attribute__((ext_vector_type(4))) short short4v;
typedef __attribute__((ext_vector_type(8))) __bf16 bf16x8;
typedef __attribute__((ext_vector_type(4))) float f32x4;
typedef __attribute__((ext_vector_type(16))) float f32x16;
typedef __attribute__((ext_vector_type(4))) unsigned int u32x4;

__device__ inline unsigned short f2bf(float x) {
  unsigned int u = __builtin_bit_cast(unsigned int, x);
  unsigned int r = (u + 0x7fffu + ((u >> 16) & 1u)) >> 16;
  return (unsigned short)r;
}
__device__ inline float bf2f(unsigned short b) {
  unsigned int u = ((unsigned int)b) << 16;
  return __builtin_bit_cast(float, u);
}
__device__ inline unsigned int pk2(float a, float b) {
  unsigned short ua = __builtin_bit_cast(unsigned short, (__bf16)a);
  unsigned short ub = __builtin_bit_cast(unsigned short, (__bf16)b);
  return (unsigned int)ua | ((unsigned int)ub << 16);
}

// ---------------------------------------------------------------------------
// bf16 MFMA GEMM (proven R20): 128x128, BK=32, 3-buffer ring, vmcnt(4),
// one barrier/iter, conflict-free (row>>1)&3 swizzle, zero bank conflicts.
// ---------------------------------------------------------------------------
template <bool BF16_OUT, bool SPLIT>
__global__ __launch_bounds__(256) void gemm_ring(
    const unsigned short* __restrict__ A, const unsigned short* __restrict__ Bt,
    void* __restrict__ C0, void* __restrict__ C1,
    int M, int N, int K, int Nsplit, int S0, int S1) {
  __shared__ __align__(16) unsigned short lds[3 * 8192];  // 49152 B
  const int t    = threadIdx.x;
  const int lane = t & 63;
  const int w    = t >> 6;
  const int lg   = lane >> 4, l15 = lane & 15;
  const int wr   = w >> 1,    wc  = w & 1;
  const int bm = blockIdx.y * 128, bn = blockIdx.x * 128;

  const int r0  = t >> 2;
  const int c8  = (t & 3) ^ ((r0 >> 1) & 3);
  const int dst = t * 8;
  const int rk  = (l15 >> 1) & 3;

#define STAGE(kt, b)                                                           \
  { _Pragma("unroll") for (int i = 0; i < 2; ++i) {                            \
      __builtin_amdgcn_global_load_lds(                                        \
          (const __attribute__((address_space(1))) unsigned int*)              \
              &A[(size_t)(bm + i * 64 + r0) * K + (kt) * 32 + c8 * 8],         \
          (__attribute__((address_space(3))) unsigned int*)                    \
              &lds[(b) * 8192 + i * 2048 + dst],                               \
          16, 0, 0);                                                           \
      __builtin_amdgcn_global_load_lds(                                        \
          (const __attribute__((address_space(1))) unsigned int*)              \
              &Bt[(size_t)(bn + i * 64 + r0) * K + (kt) * 32 + c8 * 8],        \
          (__attribute__((address_space(3))) unsigned int*)                    \
              &lds[(b) * 8192 + 4096 + i * 2048 + dst],                        \
          16, 0, 0);                                                           \
  } }

  f32x4 acc[4][4];
#pragma unroll
  for (int m = 0; m < 4; ++m)
#pragma unroll
    for (int n = 0; n < 4; ++n) acc[m][n] = (f32x4){0.f, 0.f, 0.f, 0.f};

  const int NT = K >> 5;
  STAGE(0, 0)
  STAGE(1, 1)
  int bc = 0;

  for (int kt = 0; kt < NT; ++kt) {
    if (kt + 1 < NT) {
      asm volatile("s_waitcnt vmcnt(4)" ::: "memory");
    } else {
      asm volatile("s_waitcnt vmcnt(0)" ::: "memory");
    }
    __builtin_amdgcn_s_barrier();
    __builtin_amdgcn_sched_barrier(0);

    if (kt + 2 < NT) {
      const int nb = bc + 2 >= 3 ? bc - 1 : bc + 2;
      STAGE(kt + 2, nb)
    }

    const unsigned short* As = &lds[bc * 8192];
    const unsigned short* Bs = As + 4096;
    bf16x8 a[4], b[4];
#pragma unroll
    for (int m = 0; m < 4; ++m) {
      const int row = wr * 64 + m * 16 + l15;
      a[m] = __builtin_bit_cast(bf16x8, *reinterpret_cast<const short8v*>(
          &As[row * 32 + ((lg ^ rk) * 8)]));
    }
#pragma unroll
    for (int n = 0; n < 4; ++n) {
      const int row = wc * 64 + n * 16 + l15;
      b[n] = __builtin_bit_cast(bf16x8, *reinterpret_cast<const short8v*>(
          &Bs[row * 32 + ((lg ^ rk) * 8)]));
    }
#pragma unroll
    for (int m = 0; m < 4; ++m)
#pragma unroll
      for (int n = 0; n < 4; ++n)
        acc[m][n] = __builtin_amdgcn_mfma_f32_16x16x32_bf16(a[m], b[n], acc[m][n], 0, 0, 0);

    bc = (bc + 1 >= 3) ? 0 : bc + 1;
  }

  void* dst_p;
  int col0, stride;
  if (!SPLIT || bn < Nsplit) {
    dst_p = C0; col0 = bn; stride = S0;
  } else {
    dst_p = C1; col0 = bn - Nsplit; stride = S1;
  }
#pragma unroll
  for (int m = 0; m < 4; ++m) {
#pragma unroll
    for (int j = 0; j < 4; ++j) {
      const size_t row = (size_t)(bm + wr * 64 + m * 16 + lg * 4 + j);
#pragma unroll
      for (int n = 0; n < 4; ++n) {
        const int col = col0 + wc * 64 + n * 16 + l15;
        if (BF16_OUT)
          ((unsigned short*)dst_p)[row * stride + col] = f2bf(acc[m][n][j]);
        else
          ((float*)dst_p)[row * stride + col] = acc[m][n][j];
      }
    }
  }
#undef STAGE
}

// ---------------------------------------------------------------------------
// Fused prep: weight transposes (bx<160) + x cast (bx>=160). (proven R20/R21)
// ---------------------------------------------------------------------------
__global__ __launch_bounds__(256) void prep_all(
    const float* __restrict__ x, const float* __restrict__ Wq,
    const float* __restrict__ Wk, const float* __restrict__ Wv,
    const float* __restrict__ Wo, unsigned short* __restrict__ xb,
    unsigned short* __restrict__ Wqkvt, unsigned short* __restrict__ Wot) {
  const int bx = blockIdx.x;
  if (bx >= 160) {  // x cast: (bx-160)*64 + by over 4096 blocks
    const int cb = (bx - 160) * 64 + blockIdx.y;
    const int i = (cb * 256 + threadIdx.x) * 8;
    float4 a = *reinterpret_cast<const float4*>(&x[i]);
    float4 b = *reinterpret_cast<const float4*>(&x[i + 4]);
    short8v s;
    s[0] = f2bf(a.x); s[1] = f2bf(a.y); s[2] = f2bf(a.z); s[3] = f2bf(a.w);
    s[4] = f2bf(b.x); s[5] = f2bf(b.y); s[6] = f2bf(b.z); s[7] = f2bf(b.w);
    *reinterpret_cast<short8v*>(&xb[i]) = s;
    return;
  }
  const float* W;
  unsigned short* Wt;
  int N, nb;
  if (bx < 64)      { W = Wq; Wt = Wqkvt;                          N = 2048; nb = bx; }
  else if (bx < 80) { W = Wk; Wt = Wqkvt + (size_t)2048 * 2048;    N = 512;  nb = bx - 64; }
  else if (bx < 96) { W = Wv; Wt = Wqkvt + (size_t)2560 * 2048;    N = 512;  nb = bx - 80; }
  else              { W = Wo; Wt = Wot;                            N = 2048; nb = bx - 96; }
  const int K = 2048;
  __shared__ float tile[32][33];
  const int tx = threadIdx.x & 31, ty = threadIdx.x >> 5;
  const int n0 = nb * 32, k0 = blockIdx.y * 32;
#pragma unroll
  for (int i = 0; i < 4; ++i)
    tile[ty + i * 8][tx] = W[(size_t)(k0 + ty + i * 8) * N + n0 + tx];
  __syncthreads();
#pragma unroll
  for (int i = 0; i < 4; ++i)
    Wt[(size_t)(n0 + ty + i * 8) * K + k0 + tx] = f2bf(tile[tx][ty + i * 8]);
}

// ---------------------------------------------------------------------------
// Fused mid: RoPE+xPos (bid<20480: q then k; kvb offsets <512 only)
// + V pre-transpose (bid>=20480: kvb offsets >=512 only). (proven R21)
// ---------------------------------------------------------------------------
__global__ __launch_bounds__(256) void rope_tv_all(
    unsigned short* __restrict__ qb, unsigned short* __restrict__ kvb,
    unsigned short* __restrict__ vt) {
  const int bid = blockIdx.x;
  __shared__ unsigned short tile[64][136];
  if (bid >= 20480) {  // transpose_v region
    const int lb  = bid - 20480;
    const int st  = lb & 31;
    const int kvh = (lb >> 5) & 3;
    const int b   = lb >> 7;
    const int t = threadIdx.x;
#pragma unroll
    for (int i = 0; i < 4; ++i) {
      const int idx = t + i * 256;
      const int s   = idx >> 4;
      const int d0  = (idx & 15) * 8;
      short8v v = *reinterpret_cast<const short8v*>(
          &kvb[((size_t)(b * SLEN + st * 64 + s)) * 1024 + 512 + kvh * 128 + d0]);
      *reinterpret_cast<short8v*>(&tile[s][d0]) = v;
    }
    __syncthreads();
#pragma unroll
    for (int i = 0; i < 4; ++i) {
      const int idx = t + i * 256;
      const int d   = idx >> 3;
      const int cc  = idx & 7;
      const int cs  = cc ^ (d & 7);
      short8v o;
#pragma unroll
      for (int j = 0; j < 8; ++j) o[j] = (short)tile[cs * 8 + j][d];
      *reinterpret_cast<short8v*>(
          &vt[(((size_t)(b * 4 + kvh) * 128 + d) * 2048) + st * 64 + cc * 8]) = o;
    }
    return;
  }
  // rope region
  unsigned short* buf;
  int row_stride, nh_shift, invert, lbid;
  float extra_scale;
  if (bid < 16384) {
    buf = qb;  row_stride = 2048; nh_shift = 4; invert = 0;
    extra_scale = 0.088388347648318447f; lbid = bid;
  } else {
    buf = kvb; row_stride = 1024; nh_shift = 2; invert = 1;
    extra_scale = 1.0f; lbid = bid - 16384;
  }
  const int idx = lbid * 256 + threadIdx.x;
  const int dp  = idx & 63;
  const int tmp = idx >> 6;
  const int h   = tmp & ((1 << nh_shift) - 1);
  const int row = tmp >> nh_shift;
  const int s   = row & (SLEN - 1);

  const float inv_freq = expf(-(float)dp * (9.210340371976184f / 64.0f));
  const float ang = (float)s * inv_freq;
  float sn, cs;
  sincosf(ang, &sn, &cs);

  unsigned short* p = buf + (size_t)row * row_stride + h * HD;
  const float x0 = bf2f(p[dp]);
  const float x1 = bf2f(p[dp + 64]);
  float y0 = x0 * cs - x1 * sn;
  float y1 = x1 * cs + x0 * sn;

  const float scl = ((float)s + 256.0f) / 512.0f;
  float se_even = invert ? (1.0f / scl) : scl;
  float se_odd  = invert ? scl : (1.0f / scl);
  float se = ((dp & 1) ? se_odd : se_even) * extra_scale;

  p[dp]      = f2bf(y0 * se);
  p[dp + 64] = f2bf(y1 * se);
}

// ---------------------------------------------------------------------------
// Flash attention v12 (unchanged, proven R16-R21).
// ---------------------------------------------------------------------------
__global__ __launch_bounds__(512) void flash_attn_v12(
    const unsigned short* __restrict__ qb, const unsigned short* __restrict__ kvb,
    const unsigned short* __restrict__ vt, unsigned short* __restrict__ o) {
  const int bid = blockIdx.x;
  const int u   = bid & 7;
  const int bh  = bid >> 3;
  const int h   = bh & (NH - 1);
  const int b   = bh >> 4;
  const int kvh = h >> 2;

  __shared__ __align__(16) unsigned char smem[131072];

  const int t    = threadIdx.x;
  const int lane = t & 63;
  const int w    = t >> 6;
  const int par  = w >> 2;
  const int wq   = w & 3;
  const int hi   = lane >> 5;
  const int l31  = lane & 31;

  const size_t bS = (size_t)b * SLEN;
  const size_t vbase = (size_t)(b * 4 + kvh) * 128;

  int krow[2], kgrp[2];
#pragma unroll
  for (int i = 0; i < 2; ++i) {
    const int slot = w * 2048 + i * 1024 + lane * 16;
    krow[i] = slot >> 8;
    kgrp[i] = (slot >> 4) & 15;
  }
  int vrow[2], vchk[2];
#pragma unroll
  for (int i = 0; i < 2; ++i) {
    const int slot = w * 2048 + i * 1024 + lane * 16;
    vrow[i] = slot >> 7;
    vchk[i] = (slot >> 4) & 7;
  }

#define K_STAGE(kt, bufk)                                                      \
  { _Pragma("unroll") for (int i = 0; i < 2; ++i) {                            \
      const unsigned short* ksrc = &kvb[(bS + (size_t)(kt) * 64 + krow[i]) * 1024 \
          + kvh * 128 + ((kgrp[i] ^ (krow[i] & 15)) << 3)];                    \
      __builtin_amdgcn_global_load_lds(                                        \
          (const __attribute__((address_space(1))) unsigned int*)ksrc,         \
          (__attribute__((address_space(3))) unsigned int*)                    \
              (smem + (bufk) * 16384 + w * 2048 + i * 1024),                   \
          16, 0, 0); } }

#define V_STAGE(kt, bufk)                                                      \
  { _Pragma("unroll") for (int i = 0; i < 2; ++i) {                            \
      const unsigned short* vsrc = &vt[(vbase + vrow[i]) * 2048                \
          + (size_t)(kt) * 64 + vchk[i] * 8];                                  \
      __builtin_amdgcn_global_load_lds(                                        \
          (const __attribute__((address_space(1))) unsigned int*)vsrc,         \
          (__attribute__((address_space(3))) unsigned int*)                    \
              (smem + 65536 + (bufk) * 16384 + w * 2048 + i * 1024),           \
          16, 0, 0); } }

  for (int half = 0; half < 2; ++half) {
    const int qt2 = half ? (15 - u) : u;

    bf16x8 qf[8];
    {
      const size_t qrow = (bS + qt2 * 128 + wq * 32 + l31) * 2048 + (size_t)h * HD;
#pragma unroll
      for (int c = 0; c < 8; ++c)
        qf[c] = __builtin_bit_cast(bf16x8,
            *reinterpret_cast<const short8v*>(&qb[qrow + c * 16 + hi * 8]));
    }

    f32x16 Od[4];
#pragma unroll
    for (int ds = 0; ds < 4; ++ds)
#pragma unroll
      for (int r = 0; r < 16; ++r) Od[ds][r] = 0.f;
    float m_run = -1e30f, l_run = 0.f;

    K_STAGE(0, 0)
    K_STAGE(1, 1)
    V_STAGE(0, 0)
    V_STAGE(1, 1)
    __syncthreads();

    for (int e = 0; e <= qt2; ++e) {
      const int s = e & 1;
      const int kt = 2 * e + par;
      const bool more = (e < qt2);
      if (more) {
        K_STAGE(2 * e + 2, (s ^ 1) * 2 + 0)
        K_STAGE(2 * e + 3, (s ^ 1) * 2 + 1)
        V_STAGE(2 * e + 2, (s ^ 1) * 2 + 0)
        V_STAGE(2 * e + 3, (s ^ 1) * 2 + 1)
      }
      const unsigned short* Kb = (const unsigned short*)(smem + (s * 2 + par) * 16384);
      const unsigned int*   Vw = (const unsigned int*)(smem + 65536 + (s * 2 + par) * 16384);

      f32x16 Sa, Sb;
#pragma unroll
      for (int r = 0; r < 16; ++r) { Sa[r] = 0.f; Sb[r] = 0.f; }
      __builtin_amdgcn_s_setprio(1);
#pragma unroll
      for (int c = 0; c < 8; ++c) {
        const int ra = l31, rb = 32 + l31;
        bf16x8 ka = __builtin_bit_cast(bf16x8, *reinterpret_cast<const short8v*>(
            &Kb[ra * 128 + (((2 * c + hi) ^ (ra & 15)) << 3)]));
        bf16x8 kb2 = __builtin_bit_cast(bf16x8, *reinterpret_cast<const short8v*>(
            &Kb[rb * 128 + (((2 * c + hi) ^ (rb & 15)) << 3)]));
        Sa = __builtin_amdgcn_mfma_f32_32x32x16_bf16(ka, qf[c], Sa, 0, 0, 0);
        Sb = __builtin_amdgcn_mfma_f32_32x32x16_bf16(kb2, qf[c], Sb, 0, 0, 0);
      }
      __builtin_amdgcn_s_setprio(0);

      if (kt >= 2 * qt2) {
        const int thresh = qt2 * 128 + wq * 32 + l31 - kt * 64;
#pragma unroll
        for (int r = 0; r < 16; ++r) {
          const int kla = (r & 3) + 8 * (r >> 2) + 4 * hi;
          if (kla > thresh) Sa[r] = -INFINITY;
          if (kla + 32 > thresh) Sb[r] = -INFINITY;
        }
      }

      float pmax = Sa[0];
#pragma unroll
      for (int r = 0; r < 16; ++r) pmax = fmaxf(pmax, fmaxf(Sa[r], Sb[r]));
      pmax = fmaxf(pmax, __shfl_xor(pmax, 32));

      const bool defer = __all(pmax - m_run <= 8.0f);
      float m_new, f;
      if (defer) {
        m_new = m_run; f = 1.0f;
      } else {
        m_new = fmaxf(m_run, pmax);
        f = __expf(m_run - m_new);
        m_run = m_new;
      }

      float psum = 0.f;
#pragma unroll
      for (int r = 0; r < 16; ++r) {
        Sa[r] = __expf(Sa[r] - m_new);
        Sb[r] = __expf(Sb[r] - m_new);
        psum += Sa[r] + Sb[r];
      }
      psum += __shfl_xor(psum, 32);
      l_run = l_run * f + psum;

      if (!defer) {
#pragma unroll
        for (int ds = 0; ds < 4; ++ds)
#pragma unroll
          for (int r = 0; r < 16; ++r) Od[ds][r] *= f;
      }

#pragma unroll
      for (int kc = 0; kc < 4; ++kc) {
        const int Zz = kc & 1;
        f32x16 Sx = (kc >> 1) ? Sb : Sa;
        unsigned int W00 = pk2(Sx[4 * (2 * Zz + 0) + 0], Sx[4 * (2 * Zz + 0) + 1]);
        unsigned int W01 = pk2(Sx[4 * (2 * Zz + 0) + 2], Sx[4 * (2 * Zz + 0) + 3]);
        unsigned int W10 = pk2(Sx[4 * (2 * Zz + 1) + 0], Sx[4 * (2 * Zz + 1) + 1]);
        unsigned int W11 = pk2(Sx[4 * (2 * Zz + 1) + 2], Sx[4 * (2 * Zz + 1) + 3]);
        unsigned int X00 = __shfl_xor(W00, 32), X01 = __shfl_xor(W01, 32);
        unsigned int X10 = __shfl_xor(W10, 32), X11 = __shfl_xor(W11, 32);
        u32x4 pv;
        pv[0] = hi ? X10 : W00;
        pv[1] = hi ? X11 : W01;
        pv[2] = hi ? W10 : X00;
        pv[3] = hi ? W11 : X01;
        bf16x8 pf = __builtin_bit_cast(bf16x8, pv);
        __builtin_amdgcn_s_setprio(1);
#pragma unroll
        for (int ds = 0; ds < 4; ++ds) {
          const int d = ds * 32 + l31;
          u32x4 vv = *reinterpret_cast<const u32x4*>(
              &Vw[d * 32 + ((kc * 8 + hi * 4) ^ ((d & 7) << 2))]);
          bf16x8 vf = __builtin_bit_cast(bf16x8, vv);
          Od[ds] = __builtin_amdgcn_mfma_f32_32x32x16_bf16(vf, pf, Od[ds], 0, 0, 0);
        }
        __builtin_amdgcn_s_setprio(0);
      }

      __syncthreads();
    }

    float* mf = (float*)smem;
    float* Of = (float*)(smem + 2048);
    if (par == 1) {
      mf[(wq * 2 + 0) * 64 + lane] = m_run;
      mf[(wq * 2 + 1) * 64 + lane] = l_run;
    }
    float fe = 0.f, fo = 0.f, linv = 0.f;
#pragma unroll
    for (int p = 0; p < 2; ++p) {
      if (par == 1) {
#pragma unroll
        for (int d2 = 0; d2 < 2; ++d2)
#pragma unroll
          for (int r = 0; r < 16; ++r)
            Of[((wq * 2 + d2) * 16 + r) * 64 + lane] = Od[p * 2 + d2][r];
      }
      __syncthreads();
      if (par == 0) {
        if (p == 0) {
          const float m_o = mf[(wq * 2 + 0) * 64 + lane];
          const float l_o = mf[(wq * 2 + 1) * 64 + lane];
          const float mm = fmaxf(m_run, m_o);
          fe = __expf(m_run - mm);
          fo = __expf(m_o - mm);
          linv = 1.0f / (l_run * fe + l_o * fo);
        }
        const size_t row = bS + qt2 * 128 + wq * 32 + l31;
#pragma unroll
        for (int d2 = 0; d2 < 2; ++d2) {
          const int ds = p * 2 + d2;
#pragma unroll
          for (int g = 0; g < 4; ++g) {
            short4v ov;
#pragma unroll
            for (int j = 0; j < 4; ++j) {
              const int r = g * 4 + j;
              const float val = (Od[ds][r] * fe +
                                 Of[((wq * 2 + d2) * 16 + r) * 64 + lane] * fo) * linv;
              ov[j] = (short)__builtin_bit_cast(unsigned short, (__bf16)val);
            }
            const int dbase = ds * 32 + 8 * g + 4 * hi;
            *reinterpret_cast<short4v*>(&o[row * 2048 + h * HD + dbase]) = ov;
          }
        }
      }
      __syncthreads();
    }
  }  // half loop
#undef K_STAGE
#undef V_STAGE
}

// ---------------------------------------------------------------------------
extern "C" void kernel_launch(void* const* d_in, const int* in_sizes, int n_in,
                              void* d_out, int out_size, void* d_ws, size_t ws_size,
                              hipStream_t stream) {
  (void)in_sizes; (void)n_in; (void)out_size; (void)ws_size;
  const float* x  = (const float*)d_in[0];
  const float* Wq = (const float*)d_in[1];
  const float* Wk = (const float*)d_in[2];
  const float* Wv = (const float*)d_in[3];
  const float* Wo = (const float*)d_in[4];
  float* out = (float*)d_out;

  unsigned char* ws = (unsigned char*)d_ws;
  const size_t MB = 1024 * 1024;
  unsigned short* xb    = (unsigned short*)(ws);            // 16 MB 4096x2048
  unsigned short* Wqkvt = (unsigned short*)(ws + 16 * MB);  // 12 MB 3072x2048
  unsigned short* Wot   = (unsigned short*)(ws + 28 * MB);  //  8 MB 2048x2048
  unsigned short* qb    = (unsigned short*)(ws + 36 * MB);  // 16 MB 4096x2048
  unsigned short* kvb   = (unsigned short*)(ws + 52 * MB);  //  8 MB 4096x1024
  unsigned short* attn  = (unsigned short*)(ws + 60 * MB);  // 16 MB
  unsigned short* vtb   = (unsigned short*)(ws + 76 * MB);  //  4 MB 1024x2048

  const int M = BDIM * SLEN;  // 4096
  dim3 blk(256);

  prep_all<<<dim3(224, 64), blk, 0, stream>>>(x, Wq, Wk, Wv, Wo, xb, Wqkvt, Wot);

  gemm_ring<true, true><<<dim3(24, 32), blk, 0, stream>>>(
      xb, Wqkvt, qb, kvb, M, 3072, 2048, 2048, 2048, 1024);

  rope_tv_all<<<20736, blk, 0, stream>>>(qb, kvb, vtb);

  flash_attn_v12<<<BDIM * NH * 8, dim3(512), 0, stream>>>(qb, kvb, vtb, attn);

  gemm_ring<false, false><<<dim3(16, 32), blk, 0, stream>>>(
      attn, Wot, out, nullptr, M, 2048, 2048, 2048, 2048, 0);
}